// Round 2
// baseline (70.177 us; speedup 1.0000x reference)
//
#include <hip/hip_runtime.h>
#include <hip/hip_bf16.h>

// HeadUpdator: fused bilinear-upsample+sigmoid+einsum (MFMA, async LDS pipeline)
// + per-row gating MLP.
// feat (8,64,256,256) f32, head (8,80,64,1) f32, pred (8,80,128,128) f32
// -> out (8,80,64,1,1) f32.

using bf16x8 = __attribute__((ext_vector_type(8))) short;
using f32x4  = __attribute__((ext_vector_type(4))) float;

#define NPART 32   // row-groups per batch (each block covers 8 output rows)

__device__ __forceinline__ unsigned pk2(float lo, float hi) {
  union { __hip_bfloat162 h2; unsigned u; } cv;
  cv.h2 = __float22bfloat162_rn(make_float2(lo, hi));
  return cv.u;
}
// sigmoid(0.25a + 0.75b) with -log2e folded into the lerp weights
__device__ __forceinline__ float sigAB(float a, float b) {
  return __builtin_amdgcn_rcpf(1.0f + __builtin_amdgcn_exp2f(-0.36067376f * a - 1.08202128f * b));
}
// sigmoid(0.75a + 0.25b)
__device__ __forceinline__ float sigBA(float a, float b) {
  return __builtin_amdgcn_rcpf(1.0f + __builtin_amdgcn_exp2f(-1.08202128f * a - 0.36067376f * b));
}

// Stage one 32 KB feat half-row tile (64 ch x 128 px, f32) into LDS via
// global_load_lds. LDS layout is linear with an XOR swizzle realized by
// permuting the per-lane GLOBAL source address (G21: linear dest +
// inverse-swizzled source + swizzled read). swz(A) = A ^ (((A>>9)&7)<<4).
__device__ __forceinline__ void stage_tile(const float* __restrict__ feat,
                                           int b, int h, int hf,
                                           char* ldsbase, int tid) {
  const int wv = tid >> 6, l = tid & 63;
  const float* fb = feat + (((size_t)b * 64) << 16) + h * 256 + hf * 128;
  #pragma unroll
  for (int i = 0; i < 8; ++i) {
    const int cid = wv * 8 + i;                 // 1 KB chunk id (0..31)
    const int A   = cid * 1024 + l * 16;        // byte addr within 32 KB tile
    const int lin = A ^ (((A >> 9) & 7) << 4);  // logical (ch,px) byte addr
    const int ch  = lin >> 9;                   // 512 B per channel row
    const int px  = (lin & 511) >> 2;
    const float* src = fb + (((size_t)ch) << 16) + px;
    __builtin_amdgcn_global_load_lds(
        (const __attribute__((address_space(1))) void*)src,
        (__attribute__((address_space(3))) void*)(ldsbase + cid * 1024),
        16, 0, 0);
  }
}

// MFMA over one staged half-row tile: 4 k-steps x 5 M-tiles.
__device__ __forceinline__ void mfma_half(const char* featbuf,
                                          const unsigned short* Plds,
                                          int hf, int c0, int ch16, int kg,
                                          f32x4 acc[5]) {
  const int ch   = c0 + ch16;
  const int mask = (ch & 7) << 4;
  #pragma unroll
  for (int ks = 0; ks < 4; ++ks) {
    const int px  = ks * 32 + kg * 8;           // px within half (0..127)
    const int lin = ch * 512 + px * 4;
    const float4 f0 = *(const float4*)(featbuf + (lin ^ mask));
    const float4 f1 = *(const float4*)(featbuf + ((lin + 16) ^ mask));
    union { uint4 u; bf16x8 v; } bu;
    bu.u.x = pk2(f0.x, f0.y); bu.u.y = pk2(f0.z, f0.w);
    bu.u.z = pk2(f1.x, f1.y); bu.u.w = pk2(f1.z, f1.w);
    #pragma unroll
    for (int m = 0; m < 5; ++m) {
      const bf16x8 af = *(const bf16x8*)&Plds[(m * 16 + ch16) * 264 + hf * 128 + px];
      acc[m] = __builtin_amdgcn_mfma_f32_16x16x32_bf16(af, bu.v, acc[m], 0, 0, 0);
    }
  }
}

// ---------------- Kernel 1: assemble partials ----------------
// grid = 8*32 blocks (1/CU), 256 threads. Block (b, rb) covers rows rb*8..rb*8+7.
// Feat streams through a 3-buffer async global_load_lds pipeline; P (upsampled
// sigmoid pred row) is produced in-register (shfl neighbors) into Plds.
__global__ __launch_bounds__(256) void k_assemble(
    const float* __restrict__ feat, const float* __restrict__ pred,
    float* __restrict__ partial) {
  __shared__ __align__(16) float FeatLds[3][8192];           // 3 x 32 KB
  __shared__ __align__(16) unsigned short Plds[80 * 264];    // 42.2 KB (pad 264)

  const int tid = threadIdx.x;
  const int b  = blockIdx.x >> 5;
  const int rb = blockIdx.x & 31;
  const int wid = tid >> 6, l = tid & 63;
  const int ch16 = l & 15, kg = l >> 4;
  const int c0 = wid << 4;
  const int h0 = rb * 8;
  char* fbase = (char*)&FeatLds[0][0];

  f32x4 acc[5] = {};

  // Prologue: tiles 0 (buf0) and 1 (buf1) in flight.
  stage_tile(feat, b, h0, 0, fbase, tid);
  stage_tile(feat, b, h0, 1, fbase + 32768, tid);

  const int gg = tid & 31, nb = tid >> 5;

  for (int r = 0; r < 8; ++r) {
    const int t = 2 * r;
    const int h = h0 + r;
    // --- E1: pred loads + v-lerp into registers (consumption of these loads
    // drains the two stage-tiles issued last iteration — exactly the ones
    // consumed below; the in-order vmcnt retire leaves newer stages in flight).
    const int j = h >> 1;
    int r0, r1; float wy0, wy1;
    if ((h & 1) == 0) { r0 = (j > 0) ? j - 1 : 0; r1 = j; wy0 = 0.25f; wy1 = 0.75f; }
    else              { r0 = j; r1 = (j < 127) ? j + 1 : 127; wy0 = 0.75f; wy1 = 0.25f; }
    float y[10][4];
    #pragma unroll
    for (int i = 0; i < 10; ++i) {
      const int n = nb + 8 * i;
      const float* pb = pred + (((size_t)(b * 80 + n)) << 14);
      const float4 v0 = *(const float4*)(pb + (r0 << 7) + gg * 4);
      const float4 v1 = *(const float4*)(pb + (r1 << 7) + gg * 4);
      y[i][0] = wy0 * v0.x + wy1 * v1.x; y[i][1] = wy0 * v0.y + wy1 * v1.y;
      y[i][2] = wy0 * v0.z + wy1 * v1.z; y[i][3] = wy0 * v0.w + wy1 * v1.w;
    }
    __syncthreads();  // E2: Plds + buf[(t+2)%3] free (nothing async outstanding here)

    if (t + 2 < 16)
      stage_tile(feat, b, h0 + ((t + 2) >> 1), (t + 2) & 1,
                 fbase + ((t + 2) % 3) * 32768, tid);

    // --- E4: h-lerp + sigmoid -> Plds row (bf16). Neighbors via shfl.
    #pragma unroll
    for (int i = 0; i < 10; ++i) {
      const int n = nb + 8 * i;
      const float y0 = y[i][0], y1 = y[i][1], y2 = y[i][2], y3 = y[i][3];
      float yl = __shfl_up(y3, 1, 64);  if (gg == 0)  yl = y0;   // col 4g-1 (clamped)
      float yr = __shfl_down(y0, 1, 64); if (gg == 31) yr = y3;  // col 4g+4 (clamped)
      float P[8];
      P[0] = sigAB(yl, y0); P[1] = sigBA(y0, y1);
      P[2] = sigAB(y0, y1); P[3] = sigBA(y1, y2);
      P[4] = sigAB(y1, y2); P[5] = sigBA(y2, y3);
      P[6] = sigAB(y2, y3); P[7] = sigBA(y3, yr);
      uint4 s;
      s.x = pk2(P[0], P[1]); s.y = pk2(P[2], P[3]);
      s.z = pk2(P[4], P[5]); s.w = pk2(P[6], P[7]);
      *(uint4*)&Plds[n * 264 + gg * 8] = s;
    }
    // E5: raw barrier (NO vmcnt(0) drain — keep async stages in flight).
    asm volatile("s_waitcnt lgkmcnt(0)" ::: "memory");
    __builtin_amdgcn_s_barrier();

    mfma_half(fbase + (t % 3) * 32768, Plds, 0, c0, ch16, kg, acc);   // tile t

    // O1: raw barrier so buf[(t+3)%3] (= buf[t%3]) is free to restage.
    asm volatile("s_waitcnt lgkmcnt(0)" ::: "memory");
    __builtin_amdgcn_s_barrier();

    if (t + 3 < 16)
      stage_tile(feat, b, h0 + ((t + 3) >> 1), (t + 3) & 1,
                 fbase + ((t + 3) % 3) * 32768, tid);

    mfma_half(fbase + ((t + 1) % 3) * 32768, Plds, 1, c0, ch16, kg, acc); // tile t+1
  }

  // D frag: col = lane&15 (channel), row = (lane>>4)*4 + q (class).
  float* po = partial + ((size_t)(b * NPART + rb)) * (80 * 64);
  #pragma unroll
  for (int m = 0; m < 5; ++m) {
    #pragma unroll
    for (int q = 0; q < 4; ++q) {
      const int n = m * 16 + kg * 4 + q;
      po[n * 64 + c0 + ch16] = acc[m][q];
    }
  }
}

// ---------------- Kernel 2: reduce + head-update chain ----------------
__device__ __forceinline__ float wred64(float v) {
  #pragma unroll
  for (int off = 32; off > 0; off >>= 1) v += __shfl_xor(v, off, 64);
  return v;
}
__device__ __forceinline__ float lnorm(float x, const float* __restrict__ g,
                                       const float* __restrict__ be, int l) {
  const float m = wred64(x) * 0.015625f;
  const float d = x - m;
  const float var = wred64(d * d) * 0.015625f;
  return d * rsqrtf(var + 1e-5f) * g[l] + be[l];
}
__device__ __forceinline__ float sigmf(float x) {
  return __builtin_amdgcn_rcpf(1.0f + __builtin_amdgcn_exp2f(-1.44269504f * x));
}

__global__ __launch_bounds__(256) void k_head(
    const float* __restrict__ partial, const float* __restrict__ head,
    const float* __restrict__ Wpt, const float* __restrict__ bpt,
    const float* __restrict__ Wht, const float* __restrict__ bht,
    const float* __restrict__ Wpg, const float* __restrict__ bpg,
    const float* __restrict__ Whg, const float* __restrict__ bhg,
    const float* __restrict__ Wfc, const float* __restrict__ bfc,
    const float* __restrict__ g_pin, const float* __restrict__ be_pin,
    const float* __restrict__ g_hin, const float* __restrict__ be_hin,
    const float* __restrict__ g_pout, const float* __restrict__ be_pout,
    const float* __restrict__ g_hout, const float* __restrict__ be_hout,
    const float* __restrict__ g_fc, const float* __restrict__ be_fc,
    float* __restrict__ out) {
  __shared__ float rows[4][4][64];  // [wave][{a, hd, gate, upd}][c]
  const int tid = threadIdx.x, wid = tid >> 6, l = tid & 63;
  const int r = blockIdx.x * 4 + wid;   // grid=160 -> r in [0,640)
  const int b = r / 80, n = r % 80;

  const float* pp = partial + (size_t)b * (NPART * 80 * 64) + n * 64 + l;
  float a_c = 0.f;
  #pragma unroll 8
  for (int jj = 0; jj < NPART; ++jj) a_c += pp[(size_t)jj * (80 * 64)];
  rows[wid][0][l] = a_c;
  rows[wid][1][l] = head[(size_t)r * 64 + l];
  __syncthreads();

  float pf_in = bpt[l], pf_out = bpt[64 + l];
  float hf_in = bht[l], hf_out = bht[64 + l];
  #pragma unroll 8
  for (int c = 0; c < 64; ++c) {
    const float av = rows[wid][0][c];
    const float hv = rows[wid][1][c];
    pf_in  += av * Wpt[c * 128 + l];
    pf_out += av * Wpt[c * 128 + 64 + l];
    hf_in  += hv * Wht[c * 128 + l];
    hf_out += hv * Wht[c * 128 + 64 + l];
  }
  const float gate = hf_in * pf_in;
  rows[wid][2][l] = gate;
  __syncthreads();

  float hg = bhg[l], pg = bpg[l];
  #pragma unroll 8
  for (int c = 0; c < 64; ++c) {
    const float gv = rows[wid][2][c];
    hg += gv * Whg[c * 64 + l];
    pg += gv * Wpg[c * 64 + l];
  }
  const float head_gate = sigmf(lnorm(hg, g_hin, be_hin, l));
  const float pred_gate = sigmf(lnorm(pg, g_pin, be_pin, l));
  const float hfo = lnorm(hf_out, g_hout, be_hout, l);
  const float pfo = lnorm(pf_out, g_pout, be_pout, l);
  const float upd = pred_gate * pfo + head_gate * hfo;
  rows[wid][3][l] = upd;
  __syncthreads();

  float fc = bfc[l];
  #pragma unroll 8
  for (int c = 0; c < 64; ++c)
    fc += rows[wid][3][c] * Wfc[c * 64 + l];
  float o = lnorm(fc, g_fc, be_fc, l);
  o = fmaxf(o, 0.f);
  out[(size_t)r * 64 + l] = o;
}

extern "C" void kernel_launch(void* const* d_in, const int* in_sizes, int n_in,
                              void* d_out, int out_size, void* d_ws, size_t ws_size,
                              hipStream_t stream) {
  const float* feat   = (const float*)d_in[0];
  const float* head   = (const float*)d_in[1];
  const float* pred   = (const float*)d_in[2];
  const float* Wpt    = (const float*)d_in[3];
  const float* bpt    = (const float*)d_in[4];
  const float* Wht    = (const float*)d_in[5];
  const float* bht    = (const float*)d_in[6];
  const float* Wpg    = (const float*)d_in[7];
  const float* bpg    = (const float*)d_in[8];
  const float* Whg    = (const float*)d_in[9];
  const float* bhg    = (const float*)d_in[10];
  const float* Wfc    = (const float*)d_in[11];
  const float* bfc    = (const float*)d_in[12];
  const float* g_pin  = (const float*)d_in[13];
  const float* be_pin = (const float*)d_in[14];
  const float* g_hin  = (const float*)d_in[15];
  const float* be_hin = (const float*)d_in[16];
  const float* g_pout = (const float*)d_in[17];
  const float* be_pout= (const float*)d_in[18];
  const float* g_hout = (const float*)d_in[19];
  const float* be_hout= (const float*)d_in[20];
  const float* g_fc   = (const float*)d_in[21];
  const float* be_fc  = (const float*)d_in[22];
  float* out = (float*)d_out;
  float* partial = (float*)d_ws;  // needs 8*32*80*64*4 = 5.25 MB

  hipLaunchKernelGGL(k_assemble, dim3(8 * NPART), dim3(256), 0, stream,
                     feat, pred, partial);
  hipLaunchKernelGGL(k_head, dim3(160), dim3(256), 0, stream,
                     partial, head, Wpt, bpt, Wht, bht, Wpg, bpg, Whg, bhg,
                     Wfc, bfc, g_pin, be_pin, g_hin, be_hin, g_pout, be_pout,
                     g_hout, be_hout, g_fc, be_fc, out);
}

// Round 3
// 64.279 us; speedup vs baseline: 1.0918x; 1.0918x over previous
//
#include <hip/hip_runtime.h>
#include <hip/hip_bf16.h>

// HeadUpdator: fused bilinear-upsample+sigmoid+einsum (MFMA, register-pipelined)
// + per-row gating MLP.
// feat (8,64,256,256) f32, head (8,80,64,1) f32, pred (8,80,128,128) f32
// -> out (8,80,64,1,1) f32.

using bf16x8 = __attribute__((ext_vector_type(8))) short;
using f32x4  = __attribute__((ext_vector_type(4))) float;

#define NPART 64   // row-groups per batch (each block covers 4 output rows)

__device__ __forceinline__ unsigned pk2(float lo, float hi) {
  union { __hip_bfloat162 h2; unsigned u; } cv;
  cv.h2 = __float22bfloat162_rn(make_float2(lo, hi));
  return cv.u;
}
// sigmoid(0.25a + 0.75b), -log2e folded into the lerp weights
__device__ __forceinline__ float sigAB(float a, float b) {
  return __builtin_amdgcn_rcpf(1.0f + __builtin_amdgcn_exp2f(-0.36067376f * a - 1.08202128f * b));
}
// sigmoid(0.75a + 0.25b)
__device__ __forceinline__ float sigBA(float a, float b) {
  return __builtin_amdgcn_rcpf(1.0f + __builtin_amdgcn_exp2f(-1.08202128f * a - 0.36067376f * b));
}

// ---------------- Kernel 1: assemble partials ----------------
// grid = 8*64 blocks (2/CU), 256 threads, LDS 40 KB, VGPR budget 256.
// Block (b, rb) covers output rows h = rb*4..rb*4+3.
// Per row: A-phase = lerp+sigmoid pred (from prefetched regs) -> Pfrag (LDS,
// MFMA-fragment order, XOR-swizzled slots); B-phase = batch feat loads to regs,
// prefetch next row's pred to regs, cvt->bf16, 40 MFMA.
// Pfrag layout: fragment F = ks*5+m occupies bytes [F*1024, F*1024+1024);
// lane slot = kg*16 + (ch16 ^ ks)  (16B per slot).
//   read:  per (ks,m) all 64 lanes hit distinct slots of one 1KB block -> 0 conflicts.
//   write: thread (n,g): ks=g>>2, kg=g&3, slot uses (n&15)^ks -> banks spread evenly.
__global__ __launch_bounds__(256, 2) void k_assemble(
    const float* __restrict__ feat, const float* __restrict__ pred,
    float* __restrict__ partial) {
  __shared__ __align__(16) unsigned short Pfrag[40 * 64 * 8];  // 40 KB

  const int tid = threadIdx.x;
  const int b  = blockIdx.x >> 6;
  const int rb = blockIdx.x & 63;
  const int wid = tid >> 6, l = tid & 63;
  const int ch16 = l & 15, kg = l >> 4;
  const int c0 = wid << 4;
  const int h0 = rb * 4;
  const int gg = tid & 31, nb = tid >> 5;   // class n = nb + 8i, px group gg

  f32x4 acc[5] = {};

  const float* fwave = feat + (((size_t)(b * 64 + c0 + ch16)) << 16);
  const float* pbat  = pred + (((size_t)(b * 80)) << 14);

  float4 p0[10], p1[10];

  // Prologue: issue pred loads for row h0 (even: rows (j-1, j), w=(.25,.75)).
  {
    const int j = h0 >> 1;
    const int r0 = (j > 0) ? j - 1 : 0, r1 = j;
    #pragma unroll
    for (int i = 0; i < 10; ++i) {
      const int n = nb + 8 * i;
      const float* pb = pbat + (((size_t)n) << 14);
      p0[i] = *(const float4*)(pb + (r0 << 7) + gg * 4);
      p1[i] = *(const float4*)(pb + (r1 << 7) + gg * 4);
    }
  }

  #pragma unroll
  for (int r = 0; r < 4; ++r) {
    const int h = h0 + r;
    const float wy0 = (r & 1) ? 0.75f : 0.25f;
    const float wy1 = (r & 1) ? 0.25f : 0.75f;

    // ---- A: v-lerp (regs) + h-lerp + sigmoid -> Pfrag.
    #pragma unroll
    for (int i = 0; i < 10; ++i) {
      const int n = nb + 8 * i;
      const float y0 = wy0 * p0[i].x + wy1 * p1[i].x;
      const float y1 = wy0 * p0[i].y + wy1 * p1[i].y;
      const float y2 = wy0 * p0[i].z + wy1 * p1[i].z;
      const float y3 = wy0 * p0[i].w + wy1 * p1[i].w;
      float yl = __shfl_up(y3, 1, 64);   if (gg == 0)  yl = y0;  // Y[4g-1] clamped
      float yr = __shfl_down(y0, 1, 64); if (gg == 31) yr = y3;  // Y[4g+4] clamped
      float P[8];
      P[0] = sigAB(yl, y0); P[1] = sigBA(y0, y1);
      P[2] = sigAB(y0, y1); P[3] = sigBA(y1, y2);
      P[4] = sigAB(y1, y2); P[5] = sigBA(y2, y3);
      P[6] = sigAB(y2, y3); P[7] = sigBA(y3, yr);
      uint4 s;
      s.x = pk2(P[0], P[1]); s.y = pk2(P[2], P[3]);
      s.z = pk2(P[4], P[5]); s.w = pk2(P[6], P[7]);
      const int ks = gg >> 2, kgw = gg & 3;
      const int slot = kgw * 16 + ((n & 15) ^ ks);
      *(uint4*)&Pfrag[(((ks * 5 + (n >> 4)) * 64) + slot) * 8] = s;
    }
    __syncthreads();

    // ---- B: batch feat loads, prefetch next pred, cvt + MFMA.
    const float* fb = fwave + h * 256;
    float4 f[16];
    #pragma unroll
    for (int ks = 0; ks < 8; ++ks) {
      const int pw = ks * 32 + kg * 8;       // 32B contiguous per lane
      f[2 * ks]     = *(const float4*)(fb + pw);
      f[2 * ks + 1] = *(const float4*)(fb + pw + 4);
    }
    if (r < 3) {
      const int hn = h + 1;
      const int j = hn >> 1;
      int r0, r1;
      if ((hn & 1) == 0) { r0 = (j > 0) ? j - 1 : 0; r1 = j; }
      else               { r0 = j; r1 = (j < 127) ? j + 1 : 127; }
      #pragma unroll
      for (int i = 0; i < 10; ++i) {
        const int n = nb + 8 * i;
        const float* pb = pbat + (((size_t)n) << 14);
        p0[i] = *(const float4*)(pb + (r0 << 7) + gg * 4);
        p1[i] = *(const float4*)(pb + (r1 << 7) + gg * 4);
      }
    }
    #pragma unroll
    for (int ks = 0; ks < 8; ++ks) {
      const float4 f0 = f[2 * ks], f1 = f[2 * ks + 1];
      union { uint4 u; bf16x8 v; } bu;
      bu.u.x = pk2(f0.x, f0.y); bu.u.y = pk2(f0.z, f0.w);
      bu.u.z = pk2(f1.x, f1.y); bu.u.w = pk2(f1.z, f1.w);
      const int slot = kg * 16 + (ch16 ^ ks);
      #pragma unroll
      for (int m = 0; m < 5; ++m) {
        const bf16x8 af = *(const bf16x8*)&Pfrag[(((ks * 5 + m) * 64) + slot) * 8];
        acc[m] = __builtin_amdgcn_mfma_f32_16x16x32_bf16(af, bu.v, acc[m], 0, 0, 0);
      }
    }
    __syncthreads();
  }

  // D frag: col = lane&15 (channel), row = (lane>>4)*4 + q (class).
  float* po = partial + ((size_t)(b * NPART + rb)) * (80 * 64);
  #pragma unroll
  for (int m = 0; m < 5; ++m) {
    #pragma unroll
    for (int q = 0; q < 4; ++q) {
      const int n = m * 16 + kg * 4 + q;
      po[n * 64 + c0 + ch16] = acc[m][q];
    }
  }
}

// ---------------- Kernel 2: reduce + head-update chain ----------------
__device__ __forceinline__ float wred64(float v) {
  #pragma unroll
  for (int off = 32; off > 0; off >>= 1) v += __shfl_xor(v, off, 64);
  return v;
}
__device__ __forceinline__ float lnorm(float x, const float* __restrict__ g,
                                       const float* __restrict__ be, int l) {
  const float m = wred64(x) * 0.015625f;
  const float d = x - m;
  const float var = wred64(d * d) * 0.015625f;
  return d * rsqrtf(var + 1e-5f) * g[l] + be[l];
}
__device__ __forceinline__ float sigmf(float x) {
  return __builtin_amdgcn_rcpf(1.0f + __builtin_amdgcn_exp2f(-1.44269504f * x));
}

__global__ __launch_bounds__(256) void k_head(
    const float* __restrict__ partial, const float* __restrict__ head,
    const float* __restrict__ Wpt, const float* __restrict__ bpt,
    const float* __restrict__ Wht, const float* __restrict__ bht,
    const float* __restrict__ Wpg, const float* __restrict__ bpg,
    const float* __restrict__ Whg, const float* __restrict__ bhg,
    const float* __restrict__ Wfc, const float* __restrict__ bfc,
    const float* __restrict__ g_pin, const float* __restrict__ be_pin,
    const float* __restrict__ g_hin, const float* __restrict__ be_hin,
    const float* __restrict__ g_pout, const float* __restrict__ be_pout,
    const float* __restrict__ g_hout, const float* __restrict__ be_hout,
    const float* __restrict__ g_fc, const float* __restrict__ be_fc,
    float* __restrict__ out) {
  __shared__ float rows[4][4][64];  // [wave][{a, hd, gate, upd}][c]
  const int tid = threadIdx.x, wid = tid >> 6, l = tid & 63;
  const int r = blockIdx.x * 4 + wid;   // grid=160 -> r in [0,640)
  const int b = r / 80, n = r % 80;

  const float* pp = partial + (size_t)b * (NPART * 80 * 64) + n * 64 + l;
  float a_c = 0.f;
  #pragma unroll 8
  for (int jj = 0; jj < NPART; ++jj) a_c += pp[(size_t)jj * (80 * 64)];
  rows[wid][0][l] = a_c;
  rows[wid][1][l] = head[(size_t)r * 64 + l];
  __syncthreads();

  float pf_in = bpt[l], pf_out = bpt[64 + l];
  float hf_in = bht[l], hf_out = bht[64 + l];
  #pragma unroll 8
  for (int c = 0; c < 64; ++c) {
    const float av = rows[wid][0][c];
    const float hv = rows[wid][1][c];
    pf_in  += av * Wpt[c * 128 + l];
    pf_out += av * Wpt[c * 128 + 64 + l];
    hf_in  += hv * Wht[c * 128 + l];
    hf_out += hv * Wht[c * 128 + 64 + l];
  }
  const float gate = hf_in * pf_in;
  rows[wid][2][l] = gate;
  __syncthreads();

  float hg = bhg[l], pg = bpg[l];
  #pragma unroll 8
  for (int c = 0; c < 64; ++c) {
    const float gv = rows[wid][2][c];
    hg += gv * Whg[c * 64 + l];
    pg += gv * Wpg[c * 64 + l];
  }
  const float head_gate = sigmf(lnorm(hg, g_hin, be_hin, l));
  const float pred_gate = sigmf(lnorm(pg, g_pin, be_pin, l));
  const float hfo = lnorm(hf_out, g_hout, be_hout, l);
  const float pfo = lnorm(pf_out, g_pout, be_pout, l);
  const float upd = pred_gate * pfo + head_gate * hfo;
  rows[wid][3][l] = upd;
  __syncthreads();

  float fc = bfc[l];
  #pragma unroll 8
  for (int c = 0; c < 64; ++c)
    fc += rows[wid][3][c] * Wfc[c * 64 + l];
  float o = lnorm(fc, g_fc, be_fc, l);
  o = fmaxf(o, 0.f);
  out[(size_t)r * 64 + l] = o;
}

extern "C" void kernel_launch(void* const* d_in, const int* in_sizes, int n_in,
                              void* d_out, int out_size, void* d_ws, size_t ws_size,
                              hipStream_t stream) {
  const float* feat   = (const float*)d_in[0];
  const float* head   = (const float*)d_in[1];
  const float* pred   = (const float*)d_in[2];
  const float* Wpt    = (const float*)d_in[3];
  const float* bpt    = (const float*)d_in[4];
  const float* Wht    = (const float*)d_in[5];
  const float* bht    = (const float*)d_in[6];
  const float* Wpg    = (const float*)d_in[7];
  const float* bpg    = (const float*)d_in[8];
  const float* Whg    = (const float*)d_in[9];
  const float* bhg    = (const float*)d_in[10];
  const float* Wfc    = (const float*)d_in[11];
  const float* bfc    = (const float*)d_in[12];
  const float* g_pin  = (const float*)d_in[13];
  const float* be_pin = (const float*)d_in[14];
  const float* g_hin  = (const float*)d_in[15];
  const float* be_hin = (const float*)d_in[16];
  const float* g_pout = (const float*)d_in[17];
  const float* be_pout= (const float*)d_in[18];
  const float* g_hout = (const float*)d_in[19];
  const float* be_hout= (const float*)d_in[20];
  const float* g_fc   = (const float*)d_in[21];
  const float* be_fc  = (const float*)d_in[22];
  float* out = (float*)d_out;
  float* partial = (float*)d_ws;  // needs 8*64*80*64*4 = 10.5 MB

  hipLaunchKernelGGL(k_assemble, dim3(8 * NPART), dim3(256), 0, stream,
                     feat, pred, partial);
  hipLaunchKernelGGL(k_head, dim3(160), dim3(256), 0, stream,
                     partial, head, Wpt, bpt, Wht, bht, Wpg, bpg, Whg, bhg,
                     Wfc, bfc, g_pin, be_pin, g_hin, be_hin, g_pout, be_pout,
                     g_hout, be_hout, g_fc, be_fc, out);
}